// Round 8
// baseline (223.760 us; speedup 1.0000x reference)
//
#include <hip/hip_runtime.h>

typedef unsigned long long u64;
typedef unsigned int uint32;
typedef short short8 __attribute__((ext_vector_type(8)));
typedef float f32x4 __attribute__((ext_vector_type(4)));
typedef float f32x2 __attribute__((ext_vector_type(2)));

#define B_N 8192
#define L_N 1024
#define M_N 128
#define C_N 16         // chunks over L
#define CH_N 64        // steps per chunk
#define HALF_N 512
#define SL 20          // padded 16-float slice stride (even -> float4-aligned)
#define ROWF (8 * SL)  // 160 floats per staged step row

// ws layout (bytes)
#define OFF_W    0            // w[i][m]  f32: 512KB
#define OFF_R    0x80000      // r[i][m]  f32: 512KB
#define OFF_BITS 0x100000     // bits[b][16] u64: 1MB
#define OFF_LR   0x208000     // lrT[m][t] bf16: 128*1024*2 = 256KB
#define OFF_RQ   0x248000     // Rq[c][b][m] bf16: 16*8192*128*2 = 32MB

__device__ __forceinline__ unsigned short f32_bf16(float f) {
    union { float f; unsigned u; } x; x.f = f;
    unsigned u = x.u + 0x7FFFu + ((x.u >> 16) & 1u);   // RNE
    return (unsigned short)(u >> 16);
}
__device__ __forceinline__ float bf16lo(uint32 w) {
    union { unsigned u; float f; } x; x.u = w << 16; return x.f;
}
__device__ __forceinline__ float bf16hi(uint32 w) {
    union { unsigned u; float f; } x; x.u = w & 0xFFFF0000u; return x.f;
}

// ---------------- K0: pack spins to bits (inputs are 0/1) ----------------
__global__ __launch_bounds__(256) void k_pack(const int* __restrict__ inp, u64* __restrict__ bits) {
    int g = blockIdx.x * 256 + threadIdx.x;
    int v = inp[g];
    u64 m = __ballot(v != 0);
    if ((threadIdx.x & 63) == 0) bits[g >> 6] = m;   // word = b*16 + c
}

// ---- K1: merged eps tables. 128 blocks (one m) x 64 lanes (16 steps) ----
__global__ __launch_bounds__(64) void k_eps(const float* __restrict__ eps,
        float* __restrict__ w, float* __restrict__ r, unsigned short* __restrict__ lrT) {
    int m = blockIdx.x, lane = threadIdx.x;
    const float* e0 = eps + (size_t)m * L_N + lane * 16;
    const float* e1 = eps + (size_t)(M_N + m) * L_N + lane * 16;
    float a[16], b[16];
    #pragma unroll
    for (int j = 0; j < 16; j += 4) {
        *(float4*)&a[j] = *(const float4*)&e0[j];
        *(float4*)&b[j] = *(const float4*)&e1[j];
    }
    float local = 1.f;
    #pragma unroll
    for (int j = 0; j < 16; ++j) local *= a[j];
    float sc = local;
    #pragma unroll
    for (int d = 1; d < 64; d <<= 1) {
        float up = __shfl_up(sc, d);
        if (lane >= d) sc *= up;
    }
    float prev = __shfl_up(sc, 1);
    float E = (lane == 0) ? 1.f : prev;
    int i0 = lane * 16;
    #pragma unroll
    for (int j = 0; j < 16; ++j) {
        float rat = b[j] / a[j];
        w[(size_t)(i0 + j) * M_N + m] = E * (a[j] - b[j]);
        r[(size_t)(i0 + j) * M_N + m] = rat;
        lrT[(size_t)m * L_N + i0 + j] = f32_bf16(__log2f(rat));
        E *= a[j];
    }
}

// ---- K2: fused MFMA chunk log-sums + f32 cumsum + exp2 -> excl prefix ---
// 1024 blocks = (btile, m-half); wave = one 16-m tile. Chunk-serial cumsum.
__global__ __launch_bounds__(256) void k_slog2(const u64* __restrict__ bits,
        const unsigned short* __restrict__ lrT, unsigned short* __restrict__ Rq) {
    int btile = blockIdx.x >> 1;
    int half = blockIdx.x & 1;
    int wid = threadIdx.x >> 6, lane = threadIdx.x & 63;
    int col = lane & 15, quad = lane >> 4;
    int m = (half * 4 + wid) * 16 + col;
    int b_row = btile * 16 + col;
    const u64* brow = bits + (size_t)b_row * 16;
    const unsigned short* lrow = lrT + (size_t)m * L_N;

    f32x4 cum = (f32x4){0.f, 0.f, 0.f, 0.f};

    for (int c = 0; c < C_N; ++c) {
        // exclusive prefix: write exp2(cum) BEFORE accumulating chunk c
        #pragma unroll
        for (int reg = 0; reg < 4; ++reg) {
            int b = btile * 16 + quad * 4 + reg;
            Rq[((size_t)c * B_N + b) * M_N + m] = f32_bf16(exp2f(cum[reg]));
        }
        u64 wv = brow[c];
        short8 a0, a1;
        #pragma unroll
        for (int j = 0; j < 8; ++j) {
            a0[j] = (short)((((wv >> (quad * 8 + j)) & 1) != 0) ? 0x3F80 : 0);
            a1[j] = (short)((((wv >> (32 + quad * 8 + j)) & 1) != 0) ? 0x3F80 : 0);
        }
        const unsigned short* bp = lrow + c * 64 + quad * 8;
        union { uint4 u; short8 s; } bf0, bf1;
        bf0.u = *(const uint4*)bp;
        bf1.u = *(const uint4*)(bp + 32);
        cum = __builtin_amdgcn_mfma_f32_16x16x32_bf16(a0, bf0.s, cum, 0, 0, 0);
        cum = __builtin_amdgcn_mfma_f32_16x16x32_bf16(a1, bf1.s, cum, 0, 0, 0);
    }
}

// ------- K3: main loop (16-lane groups, 8 m/lane, NB=4, R2 in VGPRs) -----
__global__ __launch_bounds__(256, 4) void k_main(const u64* __restrict__ bits,
        const float* __restrict__ w, const float* __restrict__ r,
        const unsigned short* __restrict__ Rq, float* __restrict__ out) {
    __shared__ float wbuf[32 * ROWF];   // 20KB
    __shared__ float rbuf[32 * ROWF];   // 20KB
    int c = blockIdx.x & (C_N - 1);
    int bblk = blockIdx.x >> 4;
    int lane = threadIdx.x & 63, wid = threadIdx.x >> 6;
    int s = lane & 15, g = lane >> 4;          // 4 groups of 16 lanes
    int b0 = bblk * 64 + wid * 16 + g * 4;     // 4 b per group
    int b_own = b0 + (s & 3);

    // prefix load: R2[nb][j] = pair (m = s*8 + 2j, +1); one uint4 per nb
    f32x2 R2[4][4];
    #pragma unroll
    for (int nb = 0; nb < 4; ++nb) {
        uint4 pv = *(const uint4*)(Rq + ((size_t)c * B_N + (b0 + nb)) * M_N + s * 8);
        R2[nb][0] = (f32x2){bf16lo(pv.x), bf16hi(pv.x)};
        R2[nb][1] = (f32x2){bf16lo(pv.y), bf16hi(pv.y)};
        R2[nb][2] = (f32x2){bf16lo(pv.z), bf16hi(pv.z)};
        R2[nb][3] = (f32x2){bf16lo(pv.w), bf16hi(pv.w)};
    }
    int n1 = 0;
    for (int k = 0; k < c; ++k) n1 += __popcll(bits[(size_t)b_own * 16 + k]);
    int n0 = c * CH_N - n1;

    float sum = 0.f;
    for (int h = 0; h < 2; ++h) {
        __syncthreads();
        const float4* srcw = (const float4*)(w + ((size_t)c * CH_N + h * 32) * M_N);
        const float4* srcr = (const float4*)(r + ((size_t)c * CH_N + h * 32) * M_N);
        for (int t = threadIdx.x; t < 32 * 32; t += 256) {
            int i = t >> 5, mqd = t & 31;
            int dst = i * ROWF + (mqd >> 2) * SL + (mqd & 3) * 4;
            *(float4*)&wbuf[dst] = srcw[t];
            *(float4*)&rbuf[dst] = srcr[t];
        }
        __syncthreads();

        uint32 wh[4];
        #pragma unroll
        for (int nb = 0; nb < 4; ++nb)
            wh[nb] = (uint32)(bits[(size_t)(b0 + nb) * 16 + c] >> (h * 32));
        uint32 owa = (s & 1) ? wh[1] : wh[0];
        uint32 owb = (s & 1) ? wh[3] : wh[2];
        uint32 ow = (s & 2) ? owb : owa;

        // lane's 8-float half-slice: slice s>>1, half s&1 (16B aligned)
        int lbase0 = (s >> 1) * SL + (s & 1) * 8;

        for (int tt = 0; tt < 32; ++tt) {
            int base = tt * ROWF + lbase0;
            f32x4 wa = *(const f32x4*)&wbuf[base];
            f32x4 wb2 = *(const f32x4*)&wbuf[base + 4];
            f32x2 w20 = (f32x2){wa[0], wa[1]},  w21 = (f32x2){wa[2], wa[3]};
            f32x2 w22 = (f32x2){wb2[0], wb2[1]}, w23 = (f32x2){wb2[2], wb2[3]};

            float d[4];
            #pragma unroll
            for (int nb = 0; nb < 4; ++nb) {
                f32x2 acc = R2[nb][0] * w20;
                acc += R2[nb][1] * w21;
                acc += R2[nb][2] * w22;
                acc += R2[nb][3] * w23;
                d[nb] = acc[0] + acc[1];
            }
            // route-while-reduce over 16 lanes: 5 shuffles
            float xa = (s & 1) ? d[1] : d[0];
            float ya = (s & 1) ? d[0] : d[1];
            xa += __shfl_xor(ya, 1);
            float xb = (s & 1) ? d[3] : d[2];
            float yb = (s & 1) ? d[2] : d[3];
            xb += __shfl_xor(yb, 1);
            float u = (s & 2) ? xb : xa;
            float v = (s & 2) ? xa : xb;
            u += __shfl_xor(v, 2);
            u += __shfl_xor(u, 4);
            u += __shfl_xor(u, 8);
            float Dv = u;   // full sum for b_own = b0 + (s&3)

            int sbit = (ow >> tt) & 1;
            bool valid = (n0 < HALF_N) && (n1 < HALF_N);
            float y = sbit ? Dv : -Dv;
            float contr = -0.5f * __logf(1.f + __expf(2.f * y));
            sum += valid ? contr : 0.f;
            n1 += sbit; n0 += 1 - sbit;

            f32x4 ra = *(const f32x4*)&rbuf[base];
            f32x4 rb2 = *(const f32x4*)&rbuf[base + 4];
            f32x2 r20 = (f32x2){ra[0], ra[1]},  r21 = (f32x2){ra[2], ra[3]};
            f32x2 r22 = (f32x2){rb2[0], rb2[1]}, r23 = (f32x2){rb2[2], rb2[3]};
            #pragma unroll
            for (int nb = 0; nb < 4; ++nb) {
                if ((wh[nb] >> tt) & 1) {
                    R2[nb][0] *= r20;
                    R2[nb][1] *= r21;
                    R2[nb][2] *= r22;
                    R2[nb][3] *= r23;
                }
            }
        }
    }
    if (s < 4) atomicAdd(&out[b_own], sum);
}

extern "C" void kernel_launch(void* const* d_in, const int* in_sizes, int n_in,
                              void* d_out, int out_size, void* d_ws, size_t ws_size,
                              hipStream_t stream) {
    const int*   inputs  = (const int*)d_in[0];     // (B, L) int32
    const float* epsilon = (const float*)d_in[1];   // (D, M, L) f32
    float* out = (float*)d_out;                     // (B,) f32

    char* ws = (char*)d_ws;
    float* w_tab  = (float*)(ws + OFF_W);
    float* r_tab  = (float*)(ws + OFF_R);
    u64*   bits   = (u64*)  (ws + OFF_BITS);
    unsigned short* lrT = (unsigned short*)(ws + OFF_LR);
    unsigned short* Rq  = (unsigned short*)(ws + OFF_RQ);

    k_pack<<<(B_N * L_N) / 256, 256, 0, stream>>>(inputs, bits);
    k_eps<<<M_N, 64, 0, stream>>>(epsilon, w_tab, r_tab, lrT);
    hipMemsetAsync(d_out, 0, B_N * sizeof(float), stream);
    k_slog2<<<(B_N / 16) * 2, 256, 0, stream>>>(bits, lrT, Rq);
    k_main<<<(B_N / 64) * C_N, 256, 0, stream>>>(bits, w_tab, r_tab, Rq, out);
}

// Round 9
// 182.950 us; speedup vs baseline: 1.2231x; 1.2231x over previous
//
#include <hip/hip_runtime.h>

typedef unsigned long long u64;
typedef unsigned int uint32;
typedef short short8 __attribute__((ext_vector_type(8)));
typedef float f32x4 __attribute__((ext_vector_type(4)));

#define B_N 8192
#define L_N 1024
#define M_N 128
#define C_N 16         // chunks over L
#define CH_N 64        // steps per chunk
#define HALF_N 512
#define SL 20          // padded 16-float slice stride
#define ROWF (8 * SL)  // 160 floats per staged step row

// ws layout (bytes)
#define OFF_W    0            // w[i][m]  f32: 512KB
#define OFF_R    0x80000      // r[i][m]  f32: 512KB
#define OFF_BITS 0x100000     // bits[b][16] u64: 1MB
#define OFF_LR   0x208000     // lrT[m][t] bf16: 256KB
#define OFF_RQ   0x248000     // Rq[c][b][m] bf16: 32MB
#define OFF_T    0x2248000    // T[b] int32: 32KB

#define PACK_BLK (B_N * L_N / 256)   // 32768
#define EPS_BLK  32                  // 128 m / 4 per block
#define ZERO_BLK 32                  // 8192 / 256

__device__ __forceinline__ unsigned short f32_bf16(float f) {
    union { float f; unsigned u; } x; x.f = f;
    unsigned u = x.u + 0x7FFFu + ((x.u >> 16) & 1u);   // RNE
    return (unsigned short)(u >> 16);
}
__device__ __forceinline__ float bf16lo(uint32 w) {
    union { unsigned u; float f; } x; x.u = w << 16; return x.f;
}
__device__ __forceinline__ float bf16hi(uint32 w) {
    union { unsigned u; float f; } x; x.u = w & 0xFFFF0000u; return x.f;
}

// ---- K0: fused prep: spin-pack | eps tables | zero out -------------------
__global__ __launch_bounds__(256) void k_prep(const int* __restrict__ inp,
        const float* __restrict__ eps, u64* __restrict__ bits,
        float* __restrict__ w, float* __restrict__ r,
        unsigned short* __restrict__ lrT, float* __restrict__ out) {
    int bid = blockIdx.x;
    if (bid < PACK_BLK) {
        int g = bid * 256 + threadIdx.x;
        int v = inp[g];
        u64 m = __ballot(v != 0);
        if ((threadIdx.x & 63) == 0) bits[g >> 6] = m;   // word = b*16 + c
        return;
    }
    bid -= PACK_BLK;
    if (bid < EPS_BLK) {
        int wid = threadIdx.x >> 6, lane = threadIdx.x & 63;
        int m = bid * 4 + wid;
        const float* e0 = eps + (size_t)m * L_N + lane * 16;
        const float* e1 = eps + (size_t)(M_N + m) * L_N + lane * 16;
        float a[16], b[16];
        #pragma unroll
        for (int j = 0; j < 16; j += 4) {
            *(float4*)&a[j] = *(const float4*)&e0[j];
            *(float4*)&b[j] = *(const float4*)&e1[j];
        }
        float local = 1.f;
        #pragma unroll
        for (int j = 0; j < 16; ++j) local *= a[j];
        float sc = local;
        #pragma unroll
        for (int d = 1; d < 64; d <<= 1) {
            float up = __shfl_up(sc, d);
            if (lane >= d) sc *= up;
        }
        float prev = __shfl_up(sc, 1);
        float E = (lane == 0) ? 1.f : prev;
        int i0 = lane * 16;
        #pragma unroll
        for (int j = 0; j < 16; ++j) {
            float rat = b[j] / a[j];
            w[(size_t)(i0 + j) * M_N + m] = E * (a[j] - b[j]);
            r[(size_t)(i0 + j) * M_N + m] = rat;
            lrT[(size_t)m * L_N + i0 + j] = f32_bf16(__log2f(rat));
            E *= a[j];
        }
        return;
    }
    bid -= EPS_BLK;
    if (bid < ZERO_BLK) {
        out[bid * 256 + threadIdx.x] = 0.f;
    }
}

// ---- K2: fused MFMA chunk log-sums + f32 cumsum + exp2 -> excl prefix ---
// blocks [0,1024): prefix; blocks [1024,1056): per-b saturation step T.
__global__ __launch_bounds__(256) void k_slog2(const u64* __restrict__ bits,
        const unsigned short* __restrict__ lrT, unsigned short* __restrict__ Rq,
        int* __restrict__ T) {
    if (blockIdx.x >= 1024) {
        int b = (blockIdx.x - 1024) * 256 + threadIdx.x;
        const u64* brow = bits + (size_t)b * 16;
        int n1 = 0, n0 = 0, Tv = 1024;
        for (int wd = 0; wd < 16; ++wd) {
            u64 x = brow[wd];
            int pc = __popcll(x);
            if (n1 + pc < HALF_N && n0 + (64 - pc) < HALF_N) {
                n1 += pc; n0 += 64 - pc;
                continue;
            }
            // saturation inside (or at end of) this word: bit-scan
            int found = 0;
            for (int k = 0; k < 64; ++k) {
                if (n1 >= HALF_N || n0 >= HALF_N) { Tv = wd * 64 + k; found = 1; break; }
                int sb = (int)((x >> k) & 1);
                n1 += sb; n0 += 1 - sb;
            }
            if (!found) Tv = (wd + 1) * 64;   // saturated exactly at word end
            break;
        }
        T[b] = Tv;
        return;
    }
    int btile = blockIdx.x >> 1;
    int half = blockIdx.x & 1;
    int wid = threadIdx.x >> 6, lane = threadIdx.x & 63;
    int col = lane & 15, quad = lane >> 4;
    int m = (half * 4 + wid) * 16 + col;
    int b_row = btile * 16 + col;
    const u64* brow = bits + (size_t)b_row * 16;
    const unsigned short* lrow = lrT + (size_t)m * L_N;

    f32x4 cum = (f32x4){0.f, 0.f, 0.f, 0.f};

    for (int c = 0; c < C_N; ++c) {
        #pragma unroll
        for (int reg = 0; reg < 4; ++reg) {
            int b = btile * 16 + quad * 4 + reg;
            Rq[((size_t)c * B_N + b) * M_N + m] = f32_bf16(exp2f(cum[reg]));
        }
        u64 wv = brow[c];
        short8 a0, a1;
        #pragma unroll
        for (int j = 0; j < 8; ++j) {
            a0[j] = (short)((((wv >> (quad * 8 + j)) & 1) != 0) ? 0x3F80 : 0);
            a1[j] = (short)((((wv >> (32 + quad * 8 + j)) & 1) != 0) ? 0x3F80 : 0);
        }
        const unsigned short* bp = lrow + c * 64 + quad * 8;
        union { uint4 u; short8 s; } bf0, bf1;
        bf0.u = *(const uint4*)bp;
        bf1.u = *(const uint4*)(bp + 32);
        cum = __builtin_amdgcn_mfma_f32_16x16x32_bf16(a0, bf0.s, cum, 0, 0, 0);
        cum = __builtin_amdgcn_mfma_f32_16x16x32_bf16(a1, bf1.s, cum, 0, 0, 0);
    }
}

// ------- K3: main loop (R5 structure: 8-lane groups, 16 m/lane, NB=4) ----
// __launch_bounds__(256) WITHOUT min-waves: give the allocator full VGPR
// budget so R[4][16] stays in arch VGPRs (not AGPR-spilled -> no
// v_accvgpr copies). Tell: VGPR_Count should be >=128.
__global__ __launch_bounds__(256) void k_main(const u64* __restrict__ bits,
        const float* __restrict__ w, const float* __restrict__ r,
        const unsigned short* __restrict__ Rq, const int* __restrict__ T,
        float* __restrict__ out) {
    __shared__ float wbuf[32 * ROWF];   // 20KB
    __shared__ float rbuf[32 * ROWF];   // 20KB
    int c = blockIdx.x & (C_N - 1);
    int bblk = blockIdx.x >> 4;
    int lane = threadIdx.x & 63, wid = threadIdx.x >> 6;
    int s = lane & 7, g = lane >> 3;
    int b0 = bblk * 128 + wid * 32 + g * 4;
    int b_own = b0 + (s & 3);

    // prefix load: R[nb][k], m = s*16 + k
    float R[4][16];
    #pragma unroll
    for (int nb = 0; nb < 4; ++nb) {
        const uint4* src = (const uint4*)(Rq + ((size_t)c * B_N + (b0 + nb)) * M_N + s * 16);
        #pragma unroll
        for (int u_ = 0; u_ < 2; ++u_) {
            uint4 pv = src[u_];
            R[nb][u_ * 8 + 0] = bf16lo(pv.x); R[nb][u_ * 8 + 1] = bf16hi(pv.x);
            R[nb][u_ * 8 + 2] = bf16lo(pv.y); R[nb][u_ * 8 + 3] = bf16hi(pv.y);
            R[nb][u_ * 8 + 4] = bf16lo(pv.z); R[nb][u_ * 8 + 5] = bf16hi(pv.z);
            R[nb][u_ * 8 + 6] = bf16lo(pv.w); R[nb][u_ * 8 + 7] = bf16hi(pv.w);
        }
    }
    int Tb = T[b_own];

    float sum = 0.f;
    for (int h = 0; h < 2; ++h) {
        __syncthreads();
        const float4* srcw = (const float4*)(w + ((size_t)c * CH_N + h * 32) * M_N);
        const float4* srcr = (const float4*)(r + ((size_t)c * CH_N + h * 32) * M_N);
        for (int t = threadIdx.x; t < 32 * 32; t += 256) {
            int i = t >> 5, mqd = t & 31;
            int dst = i * ROWF + (mqd >> 2) * SL + (mqd & 3) * 4;
            *(float4*)&wbuf[dst] = srcw[t];
            *(float4*)&rbuf[dst] = srcr[t];
        }
        __syncthreads();

        uint32 wh[4];
        #pragma unroll
        for (int nb = 0; nb < 4; ++nb)
            wh[nb] = (uint32)(bits[(size_t)(b0 + nb) * 16 + c] >> (h * 32));
        uint32 owa = (s & 1) ? wh[1] : wh[0];
        uint32 owb = (s & 1) ? wh[3] : wh[2];
        uint32 ow = (s & 2) ? owb : owa;

        int rel = Tb - (c * CH_N + h * 32);
        uint32 vmask = (rel <= 0) ? 0u : ((rel >= 32) ? 0xFFFFFFFFu : ((1u << rel) - 1u));

        for (int tt = 0; tt < 32; ++tt) {
            int base = tt * ROWF + s * SL;
            f32x4 wa = *(const f32x4*)&wbuf[base];
            f32x4 wb = *(const f32x4*)&wbuf[base + 4];
            f32x4 wc = *(const f32x4*)&wbuf[base + 8];
            f32x4 wd = *(const f32x4*)&wbuf[base + 12];
            float d[4];
            #pragma unroll
            for (int nb = 0; nb < 4; ++nb) {
                d[nb] = R[nb][0] * wa[0] + R[nb][1] * wa[1] + R[nb][2] * wa[2] + R[nb][3] * wa[3]
                      + R[nb][4] * wb[0] + R[nb][5] * wb[1] + R[nb][6] * wb[2] + R[nb][7] * wb[3]
                      + R[nb][8] * wc[0] + R[nb][9] * wc[1] + R[nb][10] * wc[2] + R[nb][11] * wc[3]
                      + R[nb][12] * wd[0] + R[nb][13] * wd[1] + R[nb][14] * wd[2] + R[nb][15] * wd[3];
            }
            // swap-reduce: 3 shuffles, lane s ends with D for b0 + (s&3)
            float xa = (s & 1) ? d[1] : d[0];
            float ya = (s & 1) ? d[0] : d[1];
            xa += __shfl_xor(ya, 1);
            float xb = (s & 1) ? d[3] : d[2];
            float yb = (s & 1) ? d[2] : d[3];
            xb += __shfl_xor(yb, 1);
            float u2 = (s & 2) ? xb : xa;
            float v2 = (s & 2) ? xa : xb;
            u2 += __shfl_xor(v2, 2);
            u2 += __shfl_xor(u2, 4);
            float Dv = u2;

            int sbit = (ow >> tt) & 1;
            float y = sbit ? Dv : -Dv;
            float contr = -0.5f * __logf(1.f + __expf(2.f * y));
            sum += ((vmask >> tt) & 1) ? contr : 0.f;

            f32x4 ra = *(const f32x4*)&rbuf[base];
            f32x4 rb = *(const f32x4*)&rbuf[base + 4];
            f32x4 rc = *(const f32x4*)&rbuf[base + 8];
            f32x4 rd = *(const f32x4*)&rbuf[base + 12];
            #pragma unroll
            for (int nb = 0; nb < 4; ++nb) {
                if ((wh[nb] >> tt) & 1) {
                    R[nb][0] *= ra[0];  R[nb][1] *= ra[1];  R[nb][2] *= ra[2];  R[nb][3] *= ra[3];
                    R[nb][4] *= rb[0];  R[nb][5] *= rb[1];  R[nb][6] *= rb[2];  R[nb][7] *= rb[3];
                    R[nb][8] *= rc[0];  R[nb][9] *= rc[1];  R[nb][10] *= rc[2]; R[nb][11] *= rc[3];
                    R[nb][12] *= rd[0]; R[nb][13] *= rd[1]; R[nb][14] *= rd[2]; R[nb][15] *= rd[3];
                }
            }
        }
    }
    if (s < 4) atomicAdd(&out[b_own], sum);
}

extern "C" void kernel_launch(void* const* d_in, const int* in_sizes, int n_in,
                              void* d_out, int out_size, void* d_ws, size_t ws_size,
                              hipStream_t stream) {
    const int*   inputs  = (const int*)d_in[0];     // (B, L) int32
    const float* epsilon = (const float*)d_in[1];   // (D, M, L) f32
    float* out = (float*)d_out;                     // (B,) f32

    char* ws = (char*)d_ws;
    float* w_tab  = (float*)(ws + OFF_W);
    float* r_tab  = (float*)(ws + OFF_R);
    u64*   bits   = (u64*)  (ws + OFF_BITS);
    unsigned short* lrT = (unsigned short*)(ws + OFF_LR);
    unsigned short* Rq  = (unsigned short*)(ws + OFF_RQ);
    int*   T      = (int*)  (ws + OFF_T);

    k_prep<<<PACK_BLK + EPS_BLK + ZERO_BLK, 256, 0, stream>>>(
        inputs, epsilon, bits, w_tab, r_tab, lrT, out);
    k_slog2<<<1024 + 32, 256, 0, stream>>>(bits, lrT, Rq, T);
    k_main<<<(B_N / 128) * C_N, 256, 0, stream>>>(bits, w_tab, r_tab, Rq, T, out);
}